// Round 14
// baseline (1154.284 us; speedup 1.0000x reference)
//
#include <hip/hip_runtime.h>
#include <cstdint>
#include <cstddef>

#define BB 256
#define TT 250
#define DIN 700
#define H1 256
#define DOUT 20
#define BJ0 0.01f
#define BETAC 1.8f
#define DUMMY 256
#define IQSCALE 3.814697265625e-06f   // 2^-18

typedef float f32x4 __attribute__((ext_vector_type(4)));
typedef short s16x4 __attribute__((ext_vector_type(4)));
typedef int   i32x4 __attribute__((ext_vector_type(4)));

// ---------------------------------------------------------------------------
// Workspace layout:
//   sT1   (short) [701*256] @ sh 0      transposed int16 x-proj table (row 700 = 0)
//   W11hi (char)  [256*256] @ B 358912  row-major [out][in] int8-hi  (q18 = 256*hi+lo)
//   W11lo                  @ B 424448
//   W12hi                  @ B 489984
//   W12lo                  @ B 555520
//   W22hi                  @ B 621056
//   W22lo                  @ B 686592
//   wT2o  (float) [257*20] @ f 188032  (row 256 = zeros)
//   Xp    (float) [250*256*256] @ f 193172
// ---------------------------------------------------------------------------
#define BOFF_W11HI 358912
#define BOFF_W11LO 424448
#define BOFF_W12HI 489984
#define BOFF_W12LO 555520
#define BOFF_W22HI 621056
#define BOFF_W22LO 686592
#define FOFF_W2O   188032
#define FOFF_XP    193172
#define N_PREP     381204   // 179456 + 3*65536 + 5140

__device__ __forceinline__ short q18(float w) {
    float s = w * 262144.0f;
    s = fminf(fmaxf(s, -32767.0f), 32767.0f);
    return (short)__float2int_rn(s);
}

__global__ void prep_k(const float* __restrict__ w_i2h1,
                       const float* __restrict__ w_h12h1,
                       const float* __restrict__ w_h12h2,
                       const float* __restrict__ w_h22h2,
                       const float* __restrict__ w_h2o,
                       short* __restrict__ sws,
                       char* __restrict__ bws,
                       float* __restrict__ fws) {
    int i = blockIdx.x * blockDim.x + threadIdx.x;
    if (i < 179456) { int d = i >> 8, hh = i & 255;
        sws[i] = q18((d < DIN) ? w_i2h1[hh * DIN + d] : 0.f); return; }
    i -= 179456;
    if (i < 65536) { int q = (int)q18(w_h12h1[i]); int hi = (q + 128) >> 8;
        bws[BOFF_W11HI + i] = (char)hi; bws[BOFF_W11LO + i] = (char)(q - (hi << 8)); return; }
    i -= 65536;
    if (i < 65536) { int q = (int)q18(w_h12h2[i]); int hi = (q + 128) >> 8;
        bws[BOFF_W12HI + i] = (char)hi; bws[BOFF_W12LO + i] = (char)(q - (hi << 8)); return; }
    i -= 65536;
    if (i < 65536) { int q = (int)q18(w_h22h2[i]); int hi = (q + 128) >> 8;
        bws[BOFF_W22HI + i] = (char)hi; bws[BOFF_W22LO + i] = (char)(q - (hi << 8)); return; }
    i -= 65536;
    if (i < 5140)  { int j = i / 20, hh = i % 20;
        fws[FOFF_W2O + i] = (j < H1) ? w_h2o[hh * H1 + j] : 0.f; return; }
}

// ---------------------------------------------------------------------------
// xproj (R13 verbatim): Xp[t][b][h] = b_h1[h] + (Σ_{d active} sT1[d*256+h])*2^-18
// ---------------------------------------------------------------------------
__global__ __launch_bounds__(256) void xproj_k(const float* __restrict__ x,
                                               const short* __restrict__ sT1,
                                               const float* __restrict__ b_h1,
                                               float* __restrict__ Xp) {
    const int lane = threadIdx.x & 63;
    const int wv   = threadIdx.x >> 6;
    const int bt   = blockIdx.x * 4 + wv;   // grid = T*B/4 = 16000
    const int b    = bt & (BB - 1);
    const int t    = bt >> 8;

    __shared__ __align__(16) int lst[4][712];

    const float* xrow = x + ((size_t)b * TT + t) * DIN;
    float xv[11];
    #pragma unroll
    for (int c = 0; c < 11; ++c) {
        int d = c * 64 + lane;
        xv[c] = (d < DIN) ? __builtin_nontemporal_load(xrow + d) : 0.f;
    }
    int cnt = 0;
    #pragma unroll
    for (int c = 0; c < 11; ++c) {
        int d = c * 64 + lane;
        bool p = (xv[c] != 0.0f);
        unsigned long long m = __ballot(p ? 1 : 0);
        if (p) {
            int pos = cnt + __popcll(m & ((1ull << lane) - 1ull));
            lst[wv][pos] = d;
        }
        cnt += __popcll(m);
    }
    int cntp = (cnt + 7) & ~7;
    if (lane < cntp - cnt) lst[wv][cnt + lane] = DIN;
    __syncthreads();

    const int lo = lane * 4;
    int i0 = 0, i1 = 0, i2 = 0, i3 = 0;
    int j0 = 0, j1 = 0, j2 = 0, j3 = 0;
    for (int k = 0; k < cntp; k += 8) {
        int4 ja = *(const int4*)&lst[wv][k];
        int4 jb = *(const int4*)&lst[wv][k + 4];
        s16x4 w0 = *(const s16x4*)(sT1 + ((size_t)ja.x << 8) + lo);
        s16x4 w1 = *(const s16x4*)(sT1 + ((size_t)ja.y << 8) + lo);
        s16x4 w2 = *(const s16x4*)(sT1 + ((size_t)ja.z << 8) + lo);
        s16x4 w3 = *(const s16x4*)(sT1 + ((size_t)ja.w << 8) + lo);
        s16x4 w4 = *(const s16x4*)(sT1 + ((size_t)jb.x << 8) + lo);
        s16x4 w5 = *(const s16x4*)(sT1 + ((size_t)jb.y << 8) + lo);
        s16x4 w6 = *(const s16x4*)(sT1 + ((size_t)jb.z << 8) + lo);
        s16x4 w7 = *(const s16x4*)(sT1 + ((size_t)jb.w << 8) + lo);
        i0 += (w0.x + w1.x) + (w2.x + w3.x);  j0 += (w4.x + w5.x) + (w6.x + w7.x);
        i1 += (w0.y + w1.y) + (w2.y + w3.y);  j1 += (w4.y + w5.y) + (w6.y + w7.y);
        i2 += (w0.z + w1.z) + (w2.z + w3.z);  j2 += (w4.z + w5.z) + (w6.z + w7.z);
        i3 += (w0.w + w1.w) + (w2.w + w3.w);  j3 += (w4.w + w5.w) + (w6.w + w7.w);
    }
    f32x4 acc = *(const f32x4*)(b_h1 + lo);
    acc.x += (float)(i0 + j0) * IQSCALE;
    acc.y += (float)(i1 + j1) * IQSCALE;
    acc.z += (float)(i2 + j2) * IQSCALE;
    acc.w += (float)(i3 + j3) * IQSCALE;
    __builtin_nontemporal_store(acc, (f32x4*)(Xp + ((size_t)t * BB + b) * H1 + lo));
}

// ---------------------------------------------------------------------------
// rec_k: register-resident paired-i8 MFMA recurrent loop.
// Each wave holds B-fragments of its 64 output columns of W11,W12,W22 as
// int8 (hi,lo) pairs: y_int = 256*(hi·s) + (lo·s) == exact q18 int16 dot.
// A operand = spike bytes replicated across all 16 rows (row-map-proof;
// shared k-indexing between A and B makes lane→k permutation irrelevant).
// Skew (R11): iter i does U1(step i), U2(step i-1), output/softmax(step i-2).
// W2o stays a sparse LDS gather over lst2, 8-way split across threads.
// ---------------------------------------------------------------------------
__global__ __launch_bounds__(256, 1) void rec_k(
    const float* __restrict__ Xp,
    const char* __restrict__ w11hi, const char* __restrict__ w11lo,
    const char* __restrict__ w12hi, const char* __restrict__ w12lo,
    const char* __restrict__ w22hi, const char* __restrict__ w22lo,
    const float* __restrict__ wT2o,
    const float* __restrict__ b_h2, const float* __restrict__ b_o,
    const float* __restrict__ tau_adp_h1, const float* __restrict__ tau_adp_h2,
    const float* __restrict__ tau_m_h1, const float* __restrict__ tau_m_h2,
    const float* __restrict__ tau_m_o,
    float* __restrict__ out) {
    const int h    = threadIdx.x;
    const int lane = h & 63;
    const int wv   = h >> 6;
    const int b    = blockIdx.x;
    const int mrow = lane & 15;
    const int qd   = lane >> 4;

    __shared__ __align__(16) char s1buf[2][256];
    __shared__ __align__(16) char s2buf[2][256];
    __shared__ float y11[256], y12[256], y22[256];
    __shared__ float ps2o[8][33];
    __shared__ __align__(16) int lst2[288];
    __shared__ unsigned long long wm2[4];
    __shared__ float smo[DOUT];
    __shared__ float w2oL[5152];          // 257*20 used; padded for j<32 reads

    for (int i = h; i < 5140; i += 256) w2oL[i] = wT2o[i];
    s1buf[0][h] = 0; s1buf[1][h] = 0; s2buf[0][h] = 0; s2buf[1][h] = 0;

    // ---- persistent B-fragments: [tile][chunk], 16 B each ----
    i32x4 B11h[4][4], B11l[4][4], B12h[4][4], B12l[4][4], B22h[4][4], B22l[4][4];
    {
        #pragma unroll
        for (int T = 0; T < 4; ++T) {
            const size_t rb = (size_t)(64 * wv + 16 * T + mrow) * 256;
            #pragma unroll
            for (int c = 0; c < 4; ++c) {
                const size_t off = rb + 64 * c + 16 * qd;
                B11h[T][c] = *(const i32x4*)(w11hi + off);
                B11l[T][c] = *(const i32x4*)(w11lo + off);
                B12h[T][c] = *(const i32x4*)(w12hi + off);
                B12l[T][c] = *(const i32x4*)(w12lo + off);
                B22h[T][c] = *(const i32x4*)(w22hi + off);
                B22l[T][c] = *(const i32x4*)(w22lo + off);
            }
        }
    }

    const float alpha1 = expf(-1.0f / tau_m_h1[h]);
    const float ro1    = expf(-1.0f / tau_adp_h1[h]);
    const float alpha2 = expf(-1.0f / tau_m_h2[h]);
    const float ro2    = expf(-1.0f / tau_adp_h2[h]);
    const float bh2v   = b_h2[h];
    float alpo = 0.f, bov = 0.f;
    if (h < DOUT) { alpo = expf(-1.0f / tau_m_o[h]); bov = b_o[h]; }

    float mem1 = 0.f, spk1 = 0.f, bb1v = BJ0;
    float mem2 = 0.f, spk2 = 0.f, bb2v = BJ0;
    float memo = 0.f, accs = 0.f;
    int n2p = 0;

    float xp_cur = __builtin_nontemporal_load(Xp + ((size_t)b) * H1 + h);
    __syncthreads();                       // staging done

    for (int i = 0; i <= TT + 1; ++i) {
        float xp_nxt = 0.f;
        if (i + 1 < TT)
            xp_nxt = __builtin_nontemporal_load(Xp + ((size_t)(i + 1) * BB + b) * H1 + h);
        const int cur = i & 1;

        // ---- G: A-fragments (spikes replicated over rows) + 96 MFMAs ----
        i32x4 A1[4], A2[4];
        #pragma unroll
        for (int c = 0; c < 4; ++c) {
            A1[c] = *(const i32x4*)&s1buf[cur][64 * c + 16 * qd];
            A2[c] = *(const i32x4*)&s2buf[cur][64 * c + 16 * qd];
        }
        #pragma unroll
        for (int T = 0; T < 4; ++T) {
            i32x4 cAh = {0,0,0,0}, cAl = {0,0,0,0};
            i32x4 cBh = {0,0,0,0}, cBl = {0,0,0,0};
            i32x4 cCh = {0,0,0,0}, cCl = {0,0,0,0};
            #pragma unroll
            for (int c = 0; c < 4; ++c) {
                cAh = __builtin_amdgcn_mfma_i32_16x16x64_i8(A1[c], B11h[T][c], cAh, 0, 0, 0);
                cAl = __builtin_amdgcn_mfma_i32_16x16x64_i8(A1[c], B11l[T][c], cAl, 0, 0, 0);
                cBh = __builtin_amdgcn_mfma_i32_16x16x64_i8(A1[c], B12h[T][c], cBh, 0, 0, 0);
                cBl = __builtin_amdgcn_mfma_i32_16x16x64_i8(A1[c], B12l[T][c], cBl, 0, 0, 0);
                cCh = __builtin_amdgcn_mfma_i32_16x16x64_i8(A2[c], B22h[T][c], cCh, 0, 0, 0);
                cCl = __builtin_amdgcn_mfma_i32_16x16x64_i8(A2[c], B22l[T][c], cCl, 0, 0, 0);
            }
            if (lane < 16) {
                const int n0 = 64 * wv + 16 * T + lane;
                y11[n0] = (float)((cAh[0] << 8) + cAl[0]) * IQSCALE;
                y12[n0] = (float)((cBh[0] << 8) + cBl[0]) * IQSCALE;
                y22[n0] = (float)((cCh[0] << 8) + cCl[0]) * IQSCALE;
            }
        }
        // ---- W2o sparse partials over lst2 (spk2(i-2)), 8-way split ----
        {
            const int j = h & 31, seg = h >> 5;
            float po = 0.f;
            const int len = n2p >> 3;          // n2p padded to 32 -> len mult of 4
            const int k0 = seg * len;
            for (int kb = k0; kb < k0 + len; kb += 4) {
                int4 a = *(const int4*)&lst2[kb];
                po += w2oL[a.x * DOUT + j] + w2oL[a.y * DOUT + j]
                    + w2oL[a.z * DOUT + j] + w2oL[a.w * DOUT + j];
            }
            ps2o[seg][j] = po;
        }
        __syncthreads();                       // B1: y*, ps2o ready

        // ---- U-phase ----
        unsigned long long m2 = 0;
        float ns2 = 0.f;
        const bool dmo = (h < DOUT) && (i >= 2);
        if (i < TT) {
            float h1in = xp_cur + y11[h];
            bb1v = ro1 * bb1v + BETAC * (1.f - ro1) * spk1;
            mem1 = mem1 * alpha1 - bb1v * spk1 + (1.f - alpha1) * h1in;
            float ns1 = (mem1 - bb1v - BJ0) > 0.f ? 1.f : 0.f;
            spk1 = ns1;
            s1buf[cur ^ 1][h] = (char)(ns1 != 0.f);
        }
        if (i >= 1 && i <= TT) {
            float h2in = bh2v + y12[h] + y22[h];
            bb2v = ro2 * bb2v + BETAC * (1.f - ro2) * spk2;
            mem2 = mem2 * alpha2 - bb2v * spk2 + (1.f - alpha2) * h2in;
            ns2 = (mem2 - bb2v - BJ0) > 0.f ? 1.f : 0.f;
            spk2 = ns2;
            s2buf[cur ^ 1][h] = (char)(ns2 != 0.f);
            m2 = __ballot(ns2 != 0.f ? 1 : 0);
            if (lane == 0) wm2[wv] = m2;
        }
        if (dmo) {
            float rO = ((ps2o[0][h] + ps2o[1][h]) + (ps2o[2][h] + ps2o[3][h]))
                     + ((ps2o[4][h] + ps2o[5][h]) + (ps2o[6][h] + ps2o[7][h]));
            memo = memo * alpo + (1.f - alpo) * (bov + rO);
            smo[h] = memo;
        }
        __syncthreads();                       // B2: wm2/smo visible; y reads done

        // ---- rebuild lst2 <- spk2(i-1); softmax accum (step i-2) ----
        if (i >= 1 && i <= TT) {
            int pos = __popcll(m2 & ((1ull << lane) - 1ull));
            int tot = 0;
            for (int w = 0; w < 4; ++w) {
                unsigned long long mw = wm2[w];
                if (w < wv) pos += __popcll(mw);
                tot += __popcll(mw);
            }
            if (ns2 != 0.f) lst2[pos] = h;
            int np = (tot + 31) & ~31;
            if (h < np - tot) lst2[tot + h] = DUMMY;
            n2p = np;
        }
        if (dmo) {
            float mx = smo[0];
            for (int j = 1; j < DOUT; ++j) mx = fmaxf(mx, smo[j]);
            float s = 0.f;
            for (int j = 0; j < DOUT; ++j) s += expf(smo[j] - mx);
            accs += expf(memo - mx) / s;
        }
        __syncthreads();                       // B3: lst2 ready for next G

        xp_cur = xp_nxt;
    }

    if (h < DOUT) out[b * DOUT + h] = accs;
}

extern "C" void kernel_launch(void* const* d_in, const int* in_sizes, int n_in,
                              void* d_out, int out_size, void* d_ws, size_t ws_size,
                              hipStream_t stream) {
    const float* x          = (const float*)d_in[0];
    const float* w_i2h1     = (const float*)d_in[1];
    const float* w_h12h1    = (const float*)d_in[2];
    const float* w_h12h2    = (const float*)d_in[3];
    const float* w_h22h2    = (const float*)d_in[4];
    const float* w_h2o      = (const float*)d_in[5];
    const float* b_h1       = (const float*)d_in[6];
    const float* b_h2       = (const float*)d_in[7];
    const float* b_o        = (const float*)d_in[8];
    const float* tau_adp_h1 = (const float*)d_in[9];
    const float* tau_adp_h2 = (const float*)d_in[10];
    const float* tau_m_h1   = (const float*)d_in[11];
    const float* tau_m_h2   = (const float*)d_in[12];
    const float* tau_m_o    = (const float*)d_in[13];

    short* sws = (short*)d_ws;
    char*  bws = (char*)d_ws;
    float* fws = (float*)d_ws;
    const short* sT1   = sws;
    const char*  w11hi = bws + BOFF_W11HI;
    const char*  w11lo = bws + BOFF_W11LO;
    const char*  w12hi = bws + BOFF_W12HI;
    const char*  w12lo = bws + BOFF_W12LO;
    const char*  w22hi = bws + BOFF_W22HI;
    const char*  w22lo = bws + BOFF_W22LO;
    float* wT2o = fws + FOFF_W2O;
    float* Xp   = fws + FOFF_XP;

    prep_k<<<(N_PREP + 255) / 256, 256, 0, stream>>>(
        w_i2h1, w_h12h1, w_h12h2, w_h22h2, w_h2o, sws, bws, fws);

    xproj_k<<<(TT * BB) / 4, 256, 0, stream>>>(x, sT1, b_h1, Xp);

    rec_k<<<BB, 256, 0, stream>>>(Xp, w11hi, w11lo, w12hi, w12lo, w22hi, w22lo,
                                  wT2o, b_h2, b_o, tau_adp_h1, tau_adp_h2,
                                  tau_m_h1, tau_m_h2, tau_m_o,
                                  (float*)d_out);
}

// Round 15
// 1011.466 us; speedup vs baseline: 1.1412x; 1.1412x over previous
//
#include <hip/hip_runtime.h>
#include <cstdint>
#include <cstddef>

#define BB 256
#define TT 250
#define DIN 700
#define H1 256
#define H2 256
#define DOUT 20
#define BJ0 0.01f
#define BETAC 1.8f
#define DUMMY 256                 // zero row index in every padded table
#define IQSCALE 3.814697265625e-06f   // 2^-18

typedef float f32x4 __attribute__((ext_vector_type(4)));
typedef short s16x4 __attribute__((ext_vector_type(4)));

// ---------------------------------------------------------------------------
// Workspace layout. int16 tables (element offsets in shorts from ws base):
//   sT1  [701*256] @ 0        (row 700 = zeros)
//   sT11 [257*256] @ 179456   (row 256 = zeros)
//   sT12 [257*256] @ 245248
//   sT22 [257*256] @ 311040   (end: 376832 shorts = 753664 bytes)
// fp32 region (float offsets from ws base):
//   wT2o [257*20]  @ f188416  (row 256 = zeros)
//   Xp   [256*250*256] @ f193556   *** layout [b][t][h] (contiguous per b) ***
// ---------------------------------------------------------------------------
#define SOFF_T11 179456
#define SOFF_T12 245248
#define SOFF_T22 311040
#define FOFF_W2O 188416
#define FOFF_XP  193556
#define N_TRANS  381972

__device__ __forceinline__ short q18(float w) {
    float s = w * 262144.0f;
    s = fminf(fmaxf(s, -32767.0f), 32767.0f);
    return (short)__float2int_rn(s);
}

__global__ void transpose_all_k(const float* __restrict__ w_i2h1,
                                const float* __restrict__ w_h12h1,
                                const float* __restrict__ w_h12h2,
                                const float* __restrict__ w_h22h2,
                                const float* __restrict__ w_h2o,
                                short* __restrict__ sws,
                                float* __restrict__ fws) {
    int i = blockIdx.x * blockDim.x + threadIdx.x;
    if (i < 179456) { int d = i >> 8, h = i & 255;
        sws[i] = q18((d < DIN) ? w_i2h1[h * DIN + d] : 0.f); return; }
    i -= 179456;
    if (i < 65792) { int d = i >> 8, h = i & 255;
        sws[SOFF_T11 + i] = q18((d < H1) ? w_h12h1[h * H1 + d] : 0.f); return; }
    i -= 65792;
    if (i < 65792) { int d = i >> 8, h = i & 255;
        sws[SOFF_T12 + i] = q18((d < H1) ? w_h12h2[h * H1 + d] : 0.f); return; }
    i -= 65792;
    if (i < 65792) { int d = i >> 8, h = i & 255;
        sws[SOFF_T22 + i] = q18((d < H2) ? w_h22h2[h * H2 + d] : 0.f); return; }
    i -= 65792;
    if (i < 5140)  { int j = i / 20, h = i % 20;
        fws[FOFF_W2O + i] = (j < H2) ? w_h2o[h * H2 + j] : 0.f; return; }
}

// ---------------------------------------------------------------------------
// Xp[b][t][h] = b_h1[h] + (Σ_{d active} sT1[d*256+h]) * 2^-18
// CHANGE vs R13: bt -> (b = bt/250, t = bt%250), so consecutive waves read
// CONTIGUOUS x rows and write CONTIGUOUS Xp — kills the 700KB-stride scatter.
// ---------------------------------------------------------------------------
__global__ __launch_bounds__(256) void xproj_k(const float* __restrict__ x,
                                               const short* __restrict__ sT1,
                                               const float* __restrict__ b_h1,
                                               float* __restrict__ Xp) {
    const int lane = threadIdx.x & 63;
    const int wv   = threadIdx.x >> 6;
    const int bt   = blockIdx.x * 4 + wv;   // grid = B*T/4 = 16000
    const int b    = bt / TT;
    const int t    = bt - b * TT;

    __shared__ __align__(16) int lst[4][712];

    const float* xrow = x + ((size_t)b * TT + t) * DIN;
    float xv[11];
    #pragma unroll
    for (int c = 0; c < 11; ++c) {
        int d = c * 64 + lane;
        xv[c] = (d < DIN) ? __builtin_nontemporal_load(xrow + d) : 0.f;
    }
    int cnt = 0;
    #pragma unroll
    for (int c = 0; c < 11; ++c) {
        int d = c * 64 + lane;
        bool p = (xv[c] != 0.0f);
        unsigned long long m = __ballot(p ? 1 : 0);
        if (p) {
            int pos = cnt + __popcll(m & ((1ull << lane) - 1ull));
            lst[wv][pos] = d;
        }
        cnt += __popcll(m);
    }
    int cntp = (cnt + 7) & ~7;
    if (lane < cntp - cnt) lst[wv][cnt + lane] = DIN;   // zero row pad
    __syncthreads();

    const int lo = lane * 4;
    int i0 = 0, i1 = 0, i2 = 0, i3 = 0;
    int j0 = 0, j1 = 0, j2 = 0, j3 = 0;
    for (int k = 0; k < cntp; k += 8) {
        int4 ja = *(const int4*)&lst[wv][k];
        int4 jb = *(const int4*)&lst[wv][k + 4];
        s16x4 w0 = *(const s16x4*)(sT1 + ((size_t)ja.x << 8) + lo);
        s16x4 w1 = *(const s16x4*)(sT1 + ((size_t)ja.y << 8) + lo);
        s16x4 w2 = *(const s16x4*)(sT1 + ((size_t)ja.z << 8) + lo);
        s16x4 w3 = *(const s16x4*)(sT1 + ((size_t)ja.w << 8) + lo);
        s16x4 w4 = *(const s16x4*)(sT1 + ((size_t)jb.x << 8) + lo);
        s16x4 w5 = *(const s16x4*)(sT1 + ((size_t)jb.y << 8) + lo);
        s16x4 w6 = *(const s16x4*)(sT1 + ((size_t)jb.z << 8) + lo);
        s16x4 w7 = *(const s16x4*)(sT1 + ((size_t)jb.w << 8) + lo);
        i0 += (w0.x + w1.x) + (w2.x + w3.x);  j0 += (w4.x + w5.x) + (w6.x + w7.x);
        i1 += (w0.y + w1.y) + (w2.y + w3.y);  j1 += (w4.y + w5.y) + (w6.y + w7.y);
        i2 += (w0.z + w1.z) + (w2.z + w3.z);  j2 += (w4.z + w5.z) + (w6.z + w7.z);
        i3 += (w0.w + w1.w) + (w2.w + w3.w);  j3 += (w4.w + w5.w) + (w6.w + w7.w);
    }
    f32x4 acc = *(const f32x4*)(b_h1 + lo);
    acc.x += (float)(i0 + j0) * IQSCALE;
    acc.y += (float)(i1 + j1) * IQSCALE;
    acc.z += (float)(i2 + j2) * IQSCALE;
    acc.w += (float)(i3 + j3) * IQSCALE;
    // contiguous [b][t][h] write
    __builtin_nontemporal_store(acc, (f32x4*)(Xp + ((size_t)b * TT + t) * H1 + lo));
}

// Dual-table gather: 16 rows from L[k..k+16), SAME offsets into W1 and W2.
__device__ __forceinline__ void gath16d(const short* __restrict__ W1,
                                        const short* __restrict__ W2,
                                        const int* __restrict__ L, int k, int h,
                                        int& r1, int& r2) {
    int4 a = *(const int4*)(L + k);
    int4 b = *(const int4*)(L + k + 4);
    int4 c = *(const int4*)(L + k + 8);
    int4 d = *(const int4*)(L + k + 12);
    int o0  = (a.x << 8) + h, o1  = (a.y << 8) + h, o2  = (a.z << 8) + h, o3  = (a.w << 8) + h;
    int o4  = (b.x << 8) + h, o5  = (b.y << 8) + h, o6  = (b.z << 8) + h, o7  = (b.w << 8) + h;
    int o8  = (c.x << 8) + h, o9  = (c.y << 8) + h, o10 = (c.z << 8) + h, o11 = (c.w << 8) + h;
    int o12 = (d.x << 8) + h, o13 = (d.y << 8) + h, o14 = (d.z << 8) + h, o15 = (d.w << 8) + h;
    int u0 = W1[o0], u1 = W1[o1], u2  = W1[o2],  u3  = W1[o3];
    int u4 = W1[o4], u5 = W1[o5], u6  = W1[o6],  u7  = W1[o7];
    int u8 = W1[o8], u9 = W1[o9], u10 = W1[o10], u11 = W1[o11];
    int u12 = W1[o12], u13 = W1[o13], u14 = W1[o14], u15 = W1[o15];
    int v0 = W2[o0], v1 = W2[o1], v2  = W2[o2],  v3  = W2[o3];
    int v4 = W2[o4], v5 = W2[o5], v6  = W2[o6],  v7  = W2[o7];
    int v8 = W2[o8], v9 = W2[o9], v10 = W2[o10], v11 = W2[o11];
    int v12 = W2[o12], v13 = W2[o13], v14 = W2[o14], v15 = W2[o15];
    r1 += (((u0 + u1) + (u2 + u3)) + ((u4 + u5) + (u6 + u7)))
        + (((u8 + u9) + (u10 + u11)) + ((u12 + u13) + (u14 + u15)));
    r2 += (((v0 + v1) + (v2 + v3)) + ((v4 + v5) + (v6 + v7)))
        + (((v8 + v9) + (v10 + v11)) + ((v12 + v13) + (v14 + v15)));
}

// 16 gathered int16 adds (single table).
__device__ __forceinline__ int gath16i(const short* __restrict__ W,
                                       const int* __restrict__ L, int k, int h) {
    int4 a = *(const int4*)(L + k);
    int4 b = *(const int4*)(L + k + 4);
    int4 c = *(const int4*)(L + k + 8);
    int4 d = *(const int4*)(L + k + 12);
    int v0  = W[(a.x << 8) + h], v1  = W[(a.y << 8) + h];
    int v2  = W[(a.z << 8) + h], v3  = W[(a.w << 8) + h];
    int v4  = W[(b.x << 8) + h], v5  = W[(b.y << 8) + h];
    int v6  = W[(b.z << 8) + h], v7  = W[(b.w << 8) + h];
    int v8  = W[(c.x << 8) + h], v9  = W[(c.y << 8) + h];
    int v10 = W[(c.z << 8) + h], v11 = W[(c.w << 8) + h];
    int v12 = W[(d.x << 8) + h], v13 = W[(d.y << 8) + h];
    int v14 = W[(d.z << 8) + h], v15 = W[(d.w << 8) + h];
    return (((v0 + v1) + (v2 + v3)) + ((v4 + v5) + (v6 + v7)))
         + (((v8 + v9) + (v10 + v11)) + ((v12 + v13) + (v14 + v15)));
}

// 16 fp32 output-weight values from the LDS copy of W2o (stride-20).
__device__ __forceinline__ float gather16o_lds(const float* W,
                                               const int* __restrict__ L, int k, int h) {
    int4 a = *(const int4*)(L + k);
    int4 b = *(const int4*)(L + k + 4);
    int4 c = *(const int4*)(L + k + 8);
    int4 d = *(const int4*)(L + k + 12);
    float v0  = W[a.x * DOUT + h], v1  = W[a.y * DOUT + h];
    float v2  = W[a.z * DOUT + h], v3  = W[a.w * DOUT + h];
    float v4  = W[b.x * DOUT + h], v5  = W[b.y * DOUT + h];
    float v6  = W[b.z * DOUT + h], v7  = W[b.w * DOUT + h];
    float v8  = W[c.x * DOUT + h], v9  = W[c.y * DOUT + h];
    float v10 = W[c.z * DOUT + h], v11 = W[c.w * DOUT + h];
    float v12 = W[d.x * DOUT + h], v13 = W[d.y * DOUT + h];
    float v14 = W[d.z * DOUT + h], v15 = W[d.w * DOUT + h];
    return (((v0 + v1) + (v2 + v3)) + ((v4 + v5) + (v6 + v7)))
         + (((v8 + v9) + (v10 + v11)) + ((v12 + v13) + (v14 + v15)));
}

// ---------------------------------------------------------------------------
// rec_k: R13 VERBATIM except Xp layout [b][t][h] — per-block Xp prefetch now
// walks a contiguous 256KB range. Layer-pipelined (iter i: U1(i), U2(i-1),
// output/softmax(i-2)); one fused drain chain; W2o in LDS; 2 barriers/step.
// ---------------------------------------------------------------------------
__global__ __launch_bounds__(256) void rec_k(
    const float* __restrict__ Xp,
    const short* __restrict__ sT11, const short* __restrict__ sT12,
    const short* __restrict__ sT22, const float* __restrict__ wT2o,
    const float* __restrict__ b_h2, const float* __restrict__ b_o,
    const float* __restrict__ tau_adp_h1, const float* __restrict__ tau_adp_h2,
    const float* __restrict__ tau_m_h1, const float* __restrict__ tau_m_h2,
    const float* __restrict__ tau_m_o,
    float* __restrict__ out) {
    const int h    = threadIdx.x;
    const int lane = h & 63;
    const int wv   = h >> 6;
    const int b    = blockIdx.x;
    const float* __restrict__ XpB = Xp + (size_t)b * TT * H1;

    __shared__ __align__(16) int lst1[272];
    __shared__ __align__(16) int lst2[272];
    __shared__ unsigned long long wm1[4];
    __shared__ unsigned long long wm2[4];
    __shared__ float smo[DOUT];
    __shared__ float w2oL[5140];           // 257 x 20 fp32 (row 256 zeros)

    for (int i = h; i < 5140; i += 256) w2oL[i] = wT2o[i];

    const float alpha1 = expf(-1.0f / tau_m_h1[h]);
    const float ro1    = expf(-1.0f / tau_adp_h1[h]);
    const float alpha2 = expf(-1.0f / tau_m_h2[h]);
    const float ro2    = expf(-1.0f / tau_adp_h2[h]);
    const float bh2v   = b_h2[h];
    float alpo = 0.f, bov = 0.f;
    if (h < DOUT) { alpo = expf(-1.0f / tau_m_o[h]); bov = b_o[h]; }

    float mem1 = 0.f, spk1 = 0.f, bb1v = BJ0;
    float mem2 = 0.f, spk2 = 0.f, bb2v = BJ0;
    float memo = 0.f, accs = 0.f;
    int n1p = 0, n2p = 0;

    float xp_cur = __builtin_nontemporal_load(XpB + h);   // step 0
    __syncthreads();                       // w2oL staged

    for (int i = 0; i <= TT + 1; ++i) {
        float xp_nxt = 0.f;
        if (i + 1 < TT)
            xp_nxt = __builtin_nontemporal_load(XpB + (size_t)(i + 1) * H1 + h);

        // ---- G: ONE fused gather chain over lst1 (spk1(i-1)) + lst2 (spk2(i-2))
        int ir11 = 0, ir12 = 0, ir22 = 0;
        float ro = 0.f;
        const bool dmo = (h < DOUT) && (i >= 2);
        const int kmax = n1p > n2p ? n1p : n2p;
        for (int k = 0; k < kmax; k += 16) {
            if (k < n1p) gath16d(sT11, sT12, lst1, k, h, ir11, ir12);
            if (k < n2p) {
                ir22 += gath16i(sT22, lst2, k, h);
                if (dmo) ro += gather16o_lds(w2oL, lst2, k, h);
            }
        }

        // ---- U1(step i) ----
        unsigned long long m1 = 0, m2 = 0;
        float ns1 = 0.f, ns2 = 0.f;
        if (i < TT) {
            float r1 = (float)ir11 * IQSCALE;
            bb1v = ro1 * bb1v + BETAC * (1.f - ro1) * spk1;
            mem1 = mem1 * alpha1 - bb1v * spk1 + (1.f - alpha1) * (xp_cur + r1);
            ns1 = (mem1 - bb1v - BJ0) > 0.f ? 1.f : 0.f;
            spk1 = ns1;
            m1 = __ballot(ns1 != 0.f ? 1 : 0);
            if (lane == 0) wm1[wv] = m1;
        }
        // ---- U2(step i-1) ----
        if (i >= 1 && i <= TT) {
            float r23 = (float)(ir22 + ir12) * IQSCALE;
            bb2v = ro2 * bb2v + BETAC * (1.f - ro2) * spk2;
            mem2 = mem2 * alpha2 - bb2v * spk2 + (1.f - alpha2) * (bh2v + r23);
            ns2 = (mem2 - bb2v - BJ0) > 0.f ? 1.f : 0.f;
            spk2 = ns2;
            m2 = __ballot(ns2 != 0.f ? 1 : 0);
            if (lane == 0) wm2[wv] = m2;
        }
        // ---- output neuron memo(step i-2) ----
        if (dmo) {
            memo = memo * alpo + (1.f - alpo) * (bov + ro);
            smo[h] = memo;
        }
        __syncthreads();                             // B1

        // ---- rebuild lst1 <- spk1(i) ----
        if (i < TT) {
            int pos = __popcll(m1 & ((1ull << lane) - 1ull));
            int tot = 0;
            for (int w = 0; w < 4; ++w) {
                unsigned long long mw = wm1[w];
                if (w < wv) pos += __popcll(mw);
                tot += __popcll(mw);
            }
            if (ns1 != 0.f) lst1[pos] = h;
            int np = (tot + 15) & ~15;
            if (h < np - tot) lst1[tot + h] = DUMMY;
            n1p = np;
        } else {
            n1p = 0;
        }
        // ---- rebuild lst2 <- spk2(i-1) ----
        if (i >= 1 && i <= TT) {
            int pos = __popcll(m2 & ((1ull << lane) - 1ull));
            int tot = 0;
            for (int w = 0; w < 4; ++w) {
                unsigned long long mw = wm2[w];
                if (w < wv) pos += __popcll(mw);
                tot += __popcll(mw);
            }
            if (ns2 != 0.f) lst2[pos] = h;
            int np = (tot + 15) & ~15;
            if (h < np - tot) lst2[tot + h] = DUMMY;
            n2p = np;
        }
        // ---- softmax accum for step i-2 ----
        if (dmo) {
            float mx = smo[0];
            for (int j = 1; j < DOUT; ++j) mx = fmaxf(mx, smo[j]);
            float s = 0.f;
            for (int j = 0; j < DOUT; ++j) s += expf(smo[j] - mx);
            accs += expf(memo - mx) / s;
        }
        __syncthreads();                             // B2

        xp_cur = xp_nxt;
    }

    if (h < DOUT) out[b * DOUT + h] = accs;
}

extern "C" void kernel_launch(void* const* d_in, const int* in_sizes, int n_in,
                              void* d_out, int out_size, void* d_ws, size_t ws_size,
                              hipStream_t stream) {
    const float* x          = (const float*)d_in[0];
    const float* w_i2h1     = (const float*)d_in[1];
    const float* w_h12h1    = (const float*)d_in[2];
    const float* w_h12h2    = (const float*)d_in[3];
    const float* w_h22h2    = (const float*)d_in[4];
    const float* w_h2o      = (const float*)d_in[5];
    const float* b_h1       = (const float*)d_in[6];
    const float* b_h2       = (const float*)d_in[7];
    const float* b_o        = (const float*)d_in[8];
    const float* tau_adp_h1 = (const float*)d_in[9];
    const float* tau_adp_h2 = (const float*)d_in[10];
    const float* tau_m_h1   = (const float*)d_in[11];
    const float* tau_m_h2   = (const float*)d_in[12];
    const float* tau_m_o    = (const float*)d_in[13];

    short* sws = (short*)d_ws;
    float* fws = (float*)d_ws;
    const short* sT1  = sws;
    const short* sT11 = sws + SOFF_T11;
    const short* sT12 = sws + SOFF_T12;
    const short* sT22 = sws + SOFF_T22;
    float* wT2o = fws + FOFF_W2O;
    float* Xp   = fws + FOFF_XP;

    transpose_all_k<<<(N_TRANS + 255) / 256, 256, 0, stream>>>(
        w_i2h1, w_h12h1, w_h12h2, w_h22h2, w_h2o, sws, fws);

    xproj_k<<<(BB * TT) / 4, 256, 0, stream>>>(x, sT1, b_h1, Xp);

    rec_k<<<BB, 256, 0, stream>>>(Xp, sT11, sT12, sT22, wT2o,
                                  b_h2, b_o, tau_adp_h1, tau_adp_h2,
                                  tau_m_h1, tau_m_h2, tau_m_o,
                                  (float*)d_out);
}

// Round 16
// 986.140 us; speedup vs baseline: 1.1705x; 1.0257x over previous
//
#include <hip/hip_runtime.h>
#include <cstdint>
#include <cstddef>

#define BB 256
#define TT 250
#define DIN 700
#define H1 256
#define H2 256
#define DOUT 20
#define BJ0 0.01f
#define BETAC 1.8f
#define DUMMY 256                 // zero row index in every padded table
#define IQSCALE 3.814697265625e-06f   // 2^-18

typedef float f32x4 __attribute__((ext_vector_type(4)));
typedef short s16x4 __attribute__((ext_vector_type(4)));

// ---------------------------------------------------------------------------
// Workspace layout. int16 tables (element offsets in shorts from ws base):
//   sT1  [701*256] @ 0        (row 700 = zeros)
//   sT11 [257*256] @ 179456   (row 256 = zeros)
//   sT12 [257*256] @ 245248
//   sT22 [257*256] @ 311040   (end: 376832 shorts = 753664 bytes)
// fp32 region (float offsets from ws base):
//   wT2o [257*20]  @ f188416  (row 256 = zeros)
//   Xp   [256*250*256] @ f193556   layout [b][t][h] (contiguous per b)
// ---------------------------------------------------------------------------
#define SOFF_T11 179456
#define SOFF_T12 245248
#define SOFF_T22 311040
#define FOFF_W2O 188416
#define FOFF_XP  193556
#define N_TRANS  381972

__device__ __forceinline__ short q18(float w) {
    float s = w * 262144.0f;
    s = fminf(fmaxf(s, -32767.0f), 32767.0f);
    return (short)__float2int_rn(s);
}

__global__ void transpose_all_k(const float* __restrict__ w_i2h1,
                                const float* __restrict__ w_h12h1,
                                const float* __restrict__ w_h12h2,
                                const float* __restrict__ w_h22h2,
                                const float* __restrict__ w_h2o,
                                short* __restrict__ sws,
                                float* __restrict__ fws) {
    int i = blockIdx.x * blockDim.x + threadIdx.x;
    if (i < 179456) { int d = i >> 8, h = i & 255;
        sws[i] = q18((d < DIN) ? w_i2h1[h * DIN + d] : 0.f); return; }
    i -= 179456;
    if (i < 65792) { int d = i >> 8, h = i & 255;
        sws[SOFF_T11 + i] = q18((d < H1) ? w_h12h1[h * H1 + d] : 0.f); return; }
    i -= 65792;
    if (i < 65792) { int d = i >> 8, h = i & 255;
        sws[SOFF_T12 + i] = q18((d < H1) ? w_h12h2[h * H1 + d] : 0.f); return; }
    i -= 65792;
    if (i < 65792) { int d = i >> 8, h = i & 255;
        sws[SOFF_T22 + i] = q18((d < H2) ? w_h22h2[h * H2 + d] : 0.f); return; }
    i -= 65792;
    if (i < 5140)  { int j = i / 20, h = i % 20;
        fws[FOFF_W2O + i] = (j < H2) ? w_h2o[h * H2 + j] : 0.f; return; }
}

// ---------------------------------------------------------------------------
// Xp[b][t][h] = b_h1[h] + (Σ_{d active} sT1[d*256+h]) * 2^-18   (R15 verbatim)
// ---------------------------------------------------------------------------
__global__ __launch_bounds__(256) void xproj_k(const float* __restrict__ x,
                                               const short* __restrict__ sT1,
                                               const float* __restrict__ b_h1,
                                               float* __restrict__ Xp) {
    const int lane = threadIdx.x & 63;
    const int wv   = threadIdx.x >> 6;
    const int bt   = blockIdx.x * 4 + wv;   // grid = B*T/4 = 16000
    const int b    = bt / TT;
    const int t    = bt - b * TT;

    __shared__ __align__(16) int lst[4][712];

    const float* xrow = x + ((size_t)b * TT + t) * DIN;
    float xv[11];
    #pragma unroll
    for (int c = 0; c < 11; ++c) {
        int d = c * 64 + lane;
        xv[c] = (d < DIN) ? __builtin_nontemporal_load(xrow + d) : 0.f;
    }
    int cnt = 0;
    #pragma unroll
    for (int c = 0; c < 11; ++c) {
        int d = c * 64 + lane;
        bool p = (xv[c] != 0.0f);
        unsigned long long m = __ballot(p ? 1 : 0);
        if (p) {
            int pos = cnt + __popcll(m & ((1ull << lane) - 1ull));
            lst[wv][pos] = d;
        }
        cnt += __popcll(m);
    }
    int cntp = (cnt + 7) & ~7;
    if (lane < cntp - cnt) lst[wv][cnt + lane] = DIN;   // zero row pad
    __syncthreads();

    const int lo = lane * 4;
    int i0 = 0, i1 = 0, i2 = 0, i3 = 0;
    int j0 = 0, j1 = 0, j2 = 0, j3 = 0;
    for (int k = 0; k < cntp; k += 8) {
        int4 ja = *(const int4*)&lst[wv][k];
        int4 jb = *(const int4*)&lst[wv][k + 4];
        s16x4 w0 = *(const s16x4*)(sT1 + ((size_t)ja.x << 8) + lo);
        s16x4 w1 = *(const s16x4*)(sT1 + ((size_t)ja.y << 8) + lo);
        s16x4 w2 = *(const s16x4*)(sT1 + ((size_t)ja.z << 8) + lo);
        s16x4 w3 = *(const s16x4*)(sT1 + ((size_t)ja.w << 8) + lo);
        s16x4 w4 = *(const s16x4*)(sT1 + ((size_t)jb.x << 8) + lo);
        s16x4 w5 = *(const s16x4*)(sT1 + ((size_t)jb.y << 8) + lo);
        s16x4 w6 = *(const s16x4*)(sT1 + ((size_t)jb.z << 8) + lo);
        s16x4 w7 = *(const s16x4*)(sT1 + ((size_t)jb.w << 8) + lo);
        i0 += (w0.x + w1.x) + (w2.x + w3.x);  j0 += (w4.x + w5.x) + (w6.x + w7.x);
        i1 += (w0.y + w1.y) + (w2.y + w3.y);  j1 += (w4.y + w5.y) + (w6.y + w7.y);
        i2 += (w0.z + w1.z) + (w2.z + w3.z);  j2 += (w4.z + w5.z) + (w6.z + w7.z);
        i3 += (w0.w + w1.w) + (w2.w + w3.w);  j3 += (w4.w + w5.w) + (w6.w + w7.w);
    }
    f32x4 acc = *(const f32x4*)(b_h1 + lo);
    acc.x += (float)(i0 + j0) * IQSCALE;
    acc.y += (float)(i1 + j1) * IQSCALE;
    acc.z += (float)(i2 + j2) * IQSCALE;
    acc.w += (float)(i3 + j3) * IQSCALE;
    __builtin_nontemporal_store(acc, (f32x4*)(Xp + ((size_t)b * TT + t) * H1 + lo));
}

// Dual-table gather: 16 rows from L[k..k+16), SAME offsets into W1 and W2.
__device__ __forceinline__ void gath16d(const short* __restrict__ W1,
                                        const short* __restrict__ W2,
                                        const int* __restrict__ L, int k, int h,
                                        int& r1, int& r2) {
    int4 a = *(const int4*)(L + k);
    int4 b = *(const int4*)(L + k + 4);
    int4 c = *(const int4*)(L + k + 8);
    int4 d = *(const int4*)(L + k + 12);
    int o0  = (a.x << 8) + h, o1  = (a.y << 8) + h, o2  = (a.z << 8) + h, o3  = (a.w << 8) + h;
    int o4  = (b.x << 8) + h, o5  = (b.y << 8) + h, o6  = (b.z << 8) + h, o7  = (b.w << 8) + h;
    int o8  = (c.x << 8) + h, o9  = (c.y << 8) + h, o10 = (c.z << 8) + h, o11 = (c.w << 8) + h;
    int o12 = (d.x << 8) + h, o13 = (d.y << 8) + h, o14 = (d.z << 8) + h, o15 = (d.w << 8) + h;
    int u0 = W1[o0], u1 = W1[o1], u2  = W1[o2],  u3  = W1[o3];
    int u4 = W1[o4], u5 = W1[o5], u6  = W1[o6],  u7  = W1[o7];
    int u8 = W1[o8], u9 = W1[o9], u10 = W1[o10], u11 = W1[o11];
    int u12 = W1[o12], u13 = W1[o13], u14 = W1[o14], u15 = W1[o15];
    int v0 = W2[o0], v1 = W2[o1], v2  = W2[o2],  v3  = W2[o3];
    int v4 = W2[o4], v5 = W2[o5], v6  = W2[o6],  v7  = W2[o7];
    int v8 = W2[o8], v9 = W2[o9], v10 = W2[o10], v11 = W2[o11];
    int v12 = W2[o12], v13 = W2[o13], v14 = W2[o14], v15 = W2[o15];
    r1 += (((u0 + u1) + (u2 + u3)) + ((u4 + u5) + (u6 + u7)))
        + (((u8 + u9) + (u10 + u11)) + ((u12 + u13) + (u14 + u15)));
    r2 += (((v0 + v1) + (v2 + v3)) + ((v4 + v5) + (v6 + v7)))
        + (((v8 + v9) + (v10 + v11)) + ((v12 + v13) + (v14 + v15)));
}

// 16 gathered int16 adds from the LDS copy of sT22 (256-stride, lgkm path).
__device__ __forceinline__ int gath16i_lds(const short* W,
                                           const int* __restrict__ L, int k, int h) {
    int4 a = *(const int4*)(L + k);
    int4 b = *(const int4*)(L + k + 4);
    int4 c = *(const int4*)(L + k + 8);
    int4 d = *(const int4*)(L + k + 12);
    int v0  = W[(a.x << 8) + h], v1  = W[(a.y << 8) + h];
    int v2  = W[(a.z << 8) + h], v3  = W[(a.w << 8) + h];
    int v4  = W[(b.x << 8) + h], v5  = W[(b.y << 8) + h];
    int v6  = W[(b.z << 8) + h], v7  = W[(b.w << 8) + h];
    int v8  = W[(c.x << 8) + h], v9  = W[(c.y << 8) + h];
    int v10 = W[(c.z << 8) + h], v11 = W[(c.w << 8) + h];
    int v12 = W[(d.x << 8) + h], v13 = W[(d.y << 8) + h];
    int v14 = W[(d.z << 8) + h], v15 = W[(d.w << 8) + h];
    return (((v0 + v1) + (v2 + v3)) + ((v4 + v5) + (v6 + v7)))
         + (((v8 + v9) + (v10 + v11)) + ((v12 + v13) + (v14 + v15)));
}

// 16 fp32 output-weight values from the LDS copy of W2o (stride-20).
__device__ __forceinline__ float gather16o_lds(const float* W,
                                               const int* __restrict__ L, int k, int h) {
    int4 a = *(const int4*)(L + k);
    int4 b = *(const int4*)(L + k + 4);
    int4 c = *(const int4*)(L + k + 8);
    int4 d = *(const int4*)(L + k + 12);
    float v0  = W[a.x * DOUT + h], v1  = W[a.y * DOUT + h];
    float v2  = W[a.z * DOUT + h], v3  = W[a.w * DOUT + h];
    float v4  = W[b.x * DOUT + h], v5  = W[b.y * DOUT + h];
    float v6  = W[b.z * DOUT + h], v7  = W[b.w * DOUT + h];
    float v8  = W[c.x * DOUT + h], v9  = W[c.y * DOUT + h];
    float v10 = W[c.z * DOUT + h], v11 = W[c.w * DOUT + h];
    float v12 = W[d.x * DOUT + h], v13 = W[d.y * DOUT + h];
    float v14 = W[d.z * DOUT + h], v15 = W[d.w * DOUT + h];
    return (((v0 + v1) + (v2 + v3)) + ((v4 + v5) + (v6 + v7)))
         + (((v8 + v9) + (v10 + v11)) + ((v12 + v13) + (v14 + v15)));
}

// ---------------------------------------------------------------------------
// rec_k: R15 structure with sT22 LDS-RESIDENT (128.5 KB, staged once).
// Global vmcnt chain per k-group: 32 loads (sT11+sT12 over lst1) — was 48.
// sT22 + W2o gathers ride the lgkm path (shared lst2 index math) and overlap
// the global drain. LDS total ~154 KB (1 block/CU — unchanged occupancy).
// Layer-pipelined: iter i does U1(i), U2(i-1), output/softmax(i-2).
// ---------------------------------------------------------------------------
__global__ __launch_bounds__(256) void rec_k(
    const float* __restrict__ Xp,
    const short* __restrict__ sT11, const short* __restrict__ sT12,
    const short* __restrict__ sT22, const float* __restrict__ wT2o,
    const float* __restrict__ b_h2, const float* __restrict__ b_o,
    const float* __restrict__ tau_adp_h1, const float* __restrict__ tau_adp_h2,
    const float* __restrict__ tau_m_h1, const float* __restrict__ tau_m_h2,
    const float* __restrict__ tau_m_o,
    float* __restrict__ out) {
    const int h    = threadIdx.x;
    const int lane = h & 63;
    const int wv   = h >> 6;
    const int b    = blockIdx.x;
    const float* __restrict__ XpB = Xp + (size_t)b * TT * H1;

    __shared__ __align__(16) short sT22L[65792];   // 257*256 int16 = 128.5 KB
    __shared__ __align__(16) int lst1[272];
    __shared__ __align__(16) int lst2[272];
    __shared__ unsigned long long wm1[4];
    __shared__ unsigned long long wm2[4];
    __shared__ float smo[DOUT];
    __shared__ float w2oL[5140];                   // 257 x 20 fp32

    // one-time staging: sT22 (dword copy) + W2o
    {
        const int* src = (const int*)sT22;
        int* dst = (int*)sT22L;
        for (int i = h; i < 32896; i += 256) dst[i] = src[i];
        for (int i = h; i < 5140; i += 256) w2oL[i] = wT2o[i];
    }

    const float alpha1 = expf(-1.0f / tau_m_h1[h]);
    const float ro1    = expf(-1.0f / tau_adp_h1[h]);
    const float alpha2 = expf(-1.0f / tau_m_h2[h]);
    const float ro2    = expf(-1.0f / tau_adp_h2[h]);
    const float bh2v   = b_h2[h];
    float alpo = 0.f, bov = 0.f;
    if (h < DOUT) { alpo = expf(-1.0f / tau_m_o[h]); bov = b_o[h]; }

    float mem1 = 0.f, spk1 = 0.f, bb1v = BJ0;
    float mem2 = 0.f, spk2 = 0.f, bb2v = BJ0;
    float memo = 0.f, accs = 0.f;
    int n1p = 0, n2p = 0;

    float xp_cur = __builtin_nontemporal_load(XpB + h);   // step 0
    __syncthreads();                       // staging complete

    for (int i = 0; i <= TT + 1; ++i) {
        float xp_nxt = 0.f;
        if (i + 1 < TT)
            xp_nxt = __builtin_nontemporal_load(XpB + (size_t)(i + 1) * H1 + h);

        // ---- G: fused chain — global: sT11+sT12 (lst1); LDS: sT22+W2o (lst2)
        int ir11 = 0, ir12 = 0, ir22 = 0;
        float ro = 0.f;
        const bool dmo = (h < DOUT) && (i >= 2);
        const int kmax = n1p > n2p ? n1p : n2p;
        for (int k = 0; k < kmax; k += 16) {
            if (k < n1p) gath16d(sT11, sT12, lst1, k, h, ir11, ir12);
            if (k < n2p) {
                ir22 += gath16i_lds(sT22L, lst2, k, h);
                if (dmo) ro += gather16o_lds(w2oL, lst2, k, h);
            }
        }

        // ---- U1(step i) ----
        unsigned long long m1 = 0, m2 = 0;
        float ns1 = 0.f, ns2 = 0.f;
        if (i < TT) {
            float r1 = (float)ir11 * IQSCALE;
            bb1v = ro1 * bb1v + BETAC * (1.f - ro1) * spk1;
            mem1 = mem1 * alpha1 - bb1v * spk1 + (1.f - alpha1) * (xp_cur + r1);
            ns1 = (mem1 - bb1v - BJ0) > 0.f ? 1.f : 0.f;
            spk1 = ns1;
            m1 = __ballot(ns1 != 0.f ? 1 : 0);
            if (lane == 0) wm1[wv] = m1;
        }
        // ---- U2(step i-1) ----
        if (i >= 1 && i <= TT) {
            float r23 = (float)(ir22 + ir12) * IQSCALE;
            bb2v = ro2 * bb2v + BETAC * (1.f - ro2) * spk2;
            mem2 = mem2 * alpha2 - bb2v * spk2 + (1.f - alpha2) * (bh2v + r23);
            ns2 = (mem2 - bb2v - BJ0) > 0.f ? 1.f : 0.f;
            spk2 = ns2;
            m2 = __ballot(ns2 != 0.f ? 1 : 0);
            if (lane == 0) wm2[wv] = m2;
        }
        // ---- output neuron memo(step i-2) ----
        if (dmo) {
            memo = memo * alpo + (1.f - alpo) * (bov + ro);
            smo[h] = memo;
        }
        __syncthreads();                             // B1

        // ---- rebuild lst1 <- spk1(i) ----
        if (i < TT) {
            int pos = __popcll(m1 & ((1ull << lane) - 1ull));
            int tot = 0;
            for (int w = 0; w < 4; ++w) {
                unsigned long long mw = wm1[w];
                if (w < wv) pos += __popcll(mw);
                tot += __popcll(mw);
            }
            if (ns1 != 0.f) lst1[pos] = h;
            int np = (tot + 15) & ~15;
            if (h < np - tot) lst1[tot + h] = DUMMY;
            n1p = np;
        } else {
            n1p = 0;
        }
        // ---- rebuild lst2 <- spk2(i-1) ----
        if (i >= 1 && i <= TT) {
            int pos = __popcll(m2 & ((1ull << lane) - 1ull));
            int tot = 0;
            for (int w = 0; w < 4; ++w) {
                unsigned long long mw = wm2[w];
                if (w < wv) pos += __popcll(mw);
                tot += __popcll(mw);
            }
            if (ns2 != 0.f) lst2[pos] = h;
            int np = (tot + 15) & ~15;
            if (h < np - tot) lst2[tot + h] = DUMMY;
            n2p = np;
        }
        // ---- softmax accum for step i-2 ----
        if (dmo) {
            float mx = smo[0];
            for (int j = 1; j < DOUT; ++j) mx = fmaxf(mx, smo[j]);
            float s = 0.f;
            for (int j = 0; j < DOUT; ++j) s += expf(smo[j] - mx);
            accs += expf(memo - mx) / s;
        }
        __syncthreads();                             // B2

        xp_cur = xp_nxt;
    }

    if (h < DOUT) out[b * DOUT + h] = accs;
}

extern "C" void kernel_launch(void* const* d_in, const int* in_sizes, int n_in,
                              void* d_out, int out_size, void* d_ws, size_t ws_size,
                              hipStream_t stream) {
    const float* x          = (const float*)d_in[0];
    const float* w_i2h1     = (const float*)d_in[1];
    const float* w_h12h1    = (const float*)d_in[2];
    const float* w_h12h2    = (const float*)d_in[3];
    const float* w_h22h2    = (const float*)d_in[4];
    const float* w_h2o      = (const float*)d_in[5];
    const float* b_h1       = (const float*)d_in[6];
    const float* b_h2       = (const float*)d_in[7];
    const float* b_o        = (const float*)d_in[8];
    const float* tau_adp_h1 = (const float*)d_in[9];
    const float* tau_adp_h2 = (const float*)d_in[10];
    const float* tau_m_h1   = (const float*)d_in[11];
    const float* tau_m_h2   = (const float*)d_in[12];
    const float* tau_m_o    = (const float*)d_in[13];

    short* sws = (short*)d_ws;
    float* fws = (float*)d_ws;
    const short* sT1  = sws;
    const short* sT11 = sws + SOFF_T11;
    const short* sT12 = sws + SOFF_T12;
    const short* sT22 = sws + SOFF_T22;
    float* wT2o = fws + FOFF_W2O;
    float* Xp   = fws + FOFF_XP;

    transpose_all_k<<<(N_TRANS + 255) / 256, 256, 0, stream>>>(
        w_i2h1, w_h12h1, w_h12h2, w_h22h2, w_h2o, sws, fws);

    xproj_k<<<(BB * TT) / 4, 256, 0, stream>>>(x, sT1, b_h1, Xp);

    rec_k<<<BB, 256, 0, stream>>>(Xp, sT11, sT12, sT22, wT2o,
                                  b_h2, b_o, tau_adp_h1, tau_adp_h2,
                                  tau_m_h1, tau_m_h2, tau_m_o,
                                  (float*)d_out);
}